// Round 2
// baseline (205.733 us; speedup 1.0000x reference)
//
#include <hip/hip_runtime.h>

// Problem constants (from reference)
#define C_IN    7
#define NKER    586
#define KH      8
#define SEQ     4096
#define T_LEN   (SEQ * 3)      // 12288 gathered positions
#define HP      (T_LEN + 1)    // 12289 output positions
#define NC      4096           // output channels (7*585 + 1)
#define KO_N    585            // kernels per g-channel for the main block

#define H_TILE  32
#define BLOCK   256
#define CPT     4              // channels per thread (float4 store)
#define C_PER_BLOCK (BLOCK * CPT)   // 1024
#define GROW    (H_TILE + 7)   // 39 g values per channel per tile
#define GPAD    40

__global__ void conv1d_gather_kernel(
    const float* __restrict__ x,      // (SEQ, C_IN)
    const float* __restrict__ kern,   // (NKER, KH, 3)
    float* __restrict__ out)          // flat[h*NC + c]
{
    __shared__ float g[C_IN][GPAD];

    const int h0  = blockIdx.y * H_TILE;
    const int c0  = blockIdx.x * C_PER_BLOCK;
    const int tid = threadIdx.x;

    // ---- Stage g[ci][tt] for t = h0-4 .. h0+H_TILE+2 (zero outside [0,T_LEN)) ----
    for (int i = tid; i < C_IN * GROW; i += BLOCK) {
        int ci = i / GROW;
        int tt = i - ci * GROW;
        int t  = h0 - 4 + tt;
        float v = 0.0f;
        if ((unsigned)t < (unsigned)T_LEN) {
            int s  = t / 3;
            int j  = t - 3 * s;
            int si = s + j;
            si = (si > SEQ - 1) ? (SEQ - 1) : si;
            v = x[si * C_IN + ci];
        }
        g[ci][tt] = v;
    }
    __syncthreads();

    const int cbase = c0 + tid * CPT;    // multiple of 4, never equals 4095

    // ---- Per-channel taps + g-channel selection ----
    float taps[CPT][KH];
    bool  useB[CPT];
    const int ciA = cbase / KO_N;        // <= 6
    int  ciB  = ciA;
    bool anyB = false;
    #pragma unroll
    for (int j = 0; j < CPT; j++) {
        int c = cbase + j;
        int gci, kidx;
        if (c == NC - 1) { gci = 0; kidx = NKER - 1; }   // last row: g[0] * kernels[585]
        else             { gci = c / KO_N; kidx = c - KO_N * gci; }
        useB[j] = (gci != ciA);
        anyB   |= useB[j];
        if (gci != ciA) ciB = gci;
        #pragma unroll
        for (int k = 0; k < KH; k++)
            taps[j][k] = kern[kidx * (KH * 3) + k * 3 + 1];   // middle column only
    }

    float* outp = out + (size_t)h0 * NC + cbase;
    const bool waveB = __any(anyB);      // wave-uniform: does ANY lane straddle?

    if (h0 + H_TILE <= HP) {
        // ================= full 32-row tile =================
        if (!waveB) {
            // fast path: all lanes' 4 channels share g-channel ciA (14/16 waves)
            #pragma unroll
            for (int hb = 0; hb < H_TILE; hb += 8) {
                float w[15];
                #pragma unroll
                for (int i = 0; i < 15; i++) w[i] = g[ciA][hb + i];
                #pragma unroll
                for (int hh = 0; hh < 8; hh++) {
                    float d0 = 0.f, d1 = 0.f, d2 = 0.f, d3 = 0.f;
                    #pragma unroll
                    for (int k = 0; k < KH; k++) {
                        float wv = w[hh + k];
                        d0 = fmaf(wv, taps[0][k], d0);
                        d1 = fmaf(wv, taps[1][k], d1);
                        d2 = fmaf(wv, taps[2][k], d2);
                        d3 = fmaf(wv, taps[3][k], d3);
                    }
                    float4 o = {d0, d1, d2, d3};
                    *reinterpret_cast<float4*>(outp) = o;
                    outp += NC;
                }
            }
        } else {
            // straddle wave: compute both windows, select per channel
            #pragma unroll
            for (int hb = 0; hb < H_TILE; hb += 8) {
                float wA[15], wB[15];
                #pragma unroll
                for (int i = 0; i < 15; i++) { wA[i] = g[ciA][hb + i]; wB[i] = g[ciB][hb + i]; }
                #pragma unroll
                for (int hh = 0; hh < 8; hh++) {
                    float dA[CPT], dB[CPT];
                    #pragma unroll
                    for (int j = 0; j < CPT; j++) { dA[j] = 0.f; dB[j] = 0.f; }
                    #pragma unroll
                    for (int k = 0; k < KH; k++) {
                        float a = wA[hh + k], b = wB[hh + k];
                        #pragma unroll
                        for (int j = 0; j < CPT; j++) {
                            dA[j] = fmaf(a, taps[j][k], dA[j]);
                            dB[j] = fmaf(b, taps[j][k], dB[j]);
                        }
                    }
                    float4 o;
                    o.x = useB[0] ? dB[0] : dA[0];
                    o.y = useB[1] ? dB[1] : dA[1];
                    o.z = useB[2] ? dB[2] : dA[2];
                    o.w = useB[3] ? dB[3] : dA[3];
                    *reinterpret_cast<float4*>(outp) = o;
                    outp += NC;
                }
            }
        }
    } else {
        // ================= tail block (h0 = 12288, 1 row) =================
        int hend = HP - h0;
        for (int hh = 0; hh < hend; hh++) {
            float d[CPT];
            #pragma unroll
            for (int j = 0; j < CPT; j++) {
                int gci = useB[j] ? ciB : ciA;
                float acc = 0.f;
                #pragma unroll
                for (int k = 0; k < KH; k++)
                    acc = fmaf(g[gci][hh + k], taps[j][k], acc);
                d[j] = acc;
            }
            float4 o = {d[0], d[1], d[2], d[3]};
            *reinterpret_cast<float4*>(outp) = o;
            outp += NC;
        }
    }
}

extern "C" void kernel_launch(void* const* d_in, const int* in_sizes, int n_in,
                              void* d_out, int out_size, void* d_ws, size_t ws_size,
                              hipStream_t stream) {
    const float* x    = (const float*)d_in[0];   // (1, 4096, 7, 1) f32
    const float* kern = (const float*)d_in[1];   // (586, 8, 3) f32
    float* out        = (float*)d_out;           // 12289*4096 f32

    dim3 grid(NC / C_PER_BLOCK, (HP + H_TILE - 1) / H_TILE);  // (4, 385)
    conv1d_gather_kernel<<<grid, BLOCK, 0, stream>>>(x, kern, out);
}